// Round 1
// baseline (417.773 us; speedup 1.0000x reference)
//
#include <hip/hip_runtime.h>
#include <math.h>

#define NHID 1024
#define NCLS 224
#define NTPC 225
#define BATCH 2048

// ws layout (bytes):
// [0,      8192): tp   float[2048]  selected top prob per sample
// [8192,  16384): cls  int[2048]
// [16384, 24576): pos  int[2048]
// [24576, 32768): list int[2048]    sample ids grouped by class
// [32768, 33768): offs int[225]     class offsets into list

// ---------------------------------------------------------------------------
// Pass 0: label decode (int32 vs int64 autodetect), class/pos, group-by-class.
// ---------------------------------------------------------------------------
__global__ __launch_bounds__(256) void group_kernel(const int* __restrict__ labels,
                                                    int* __restrict__ cls,
                                                    int* __restrict__ pos,
                                                    int* __restrict__ list,
                                                    int* __restrict__ offs) {
    __shared__ int cnt[NCLS];
    __shared__ int nz;
    __shared__ int base[NCLS + 1];
    const int tid = threadIdx.x;
    if (tid == 0) nz = 0;
    for (int j = tid; j < NCLS; j += 256) cnt[j] = 0;
    __syncthreads();
    // dtype probe: only touch the first 2048 int32 words (valid for both dtypes).
    // int64 labels < 2^31  =>  every odd word is 0. int32: odd words are labels.
    int loc = 0;
    for (int k = 0; k < 4; ++k) {
        int i = tid + 256 * k;          // i < 1024 -> word index 2i+1 < 2048
        if (labels[2 * i + 1] != 0) loc = 1;
    }
    if (loc) atomicOr(&nz, 1);
    __syncthreads();
    const bool is64 = (nz == 0);
    int myc[8], myr[8];
#pragma unroll
    for (int k = 0; k < 8; ++k) {
        int i = tid + 256 * k;
        int l = is64 ? labels[2 * i] : labels[i];
        int c = l / NTPC;
        int p = l - c * NTPC;
        cls[i] = c;
        pos[i] = p;
        myc[k] = c;
        myr[k] = atomicAdd(&cnt[c], 1);
    }
    __syncthreads();
    if (tid == 0) {
        int s = 0;
        for (int j = 0; j < NCLS; ++j) { base[j] = s; s += cnt[j]; }
        base[NCLS] = s;
    }
    __syncthreads();
    if (tid <= NCLS) offs[tid] = base[tid];
#pragma unroll
    for (int k = 0; k < 8; ++k) {
        int i = tid + 256 * k;
        list[base[myc[k]] + myr[k]] = i;
    }
}

// ---------------------------------------------------------------------------
// Pass 1: top logits + softmax, emit tp[b] = softmax(x@Wt+bt)[b, cls[b]].
// 8 samples/block, 1024 threads = 4 K-groups x 256 class-columns.
// ---------------------------------------------------------------------------
__global__ __launch_bounds__(1024, 4) void top_kernel(const float* __restrict__ x,
                                                      const float* __restrict__ Wt,
                                                      const float* __restrict__ bt,
                                                      const int* __restrict__ cls,
                                                      float* __restrict__ tp) {
    __shared__ float lbuf[4][8][256];     // 32 KB
    const int tid  = threadIdx.x;
    const int g    = __builtin_amdgcn_readfirstlane(tid >> 8);   // K-group 0..3
    const int t    = tid & 255;                                  // class column
    const int tc   = (t < NCLS) ? t : (NCLS - 1);                // clamp for load
    const int sb   = blockIdx.x * 8;

    float acc[8];
#pragma unroll
    for (int i = 0; i < 8; ++i) acc[i] = 0.f;

    const float* xb = x + (size_t)sb * NHID + g * 256;   // uniform base
    const float* wb = Wt + (size_t)(g * 256) * NCLS + tc;

#pragma unroll 4
    for (int h = 0; h < 256; ++h) {
        float wv = wb[(size_t)h * NCLS];
#pragma unroll
        for (int i = 0; i < 8; ++i)
            acc[i] = fmaf(xb[i * NHID + h], wv, acc[i]);   // uniform x -> s_load
    }
#pragma unroll
    for (int i = 0; i < 8; ++i) lbuf[g][i][t] = acc[i];
    __syncthreads();

    const int w = tid >> 6, lane = tid & 63;
    if (w < 8) {                                  // wave w reduces sample row w
        const int r = __builtin_amdgcn_readfirstlane(w);
        float v[4];
#pragma unroll
        for (int k = 0; k < 4; ++k) {
            int tt = lane + 64 * k;
            float s = -INFINITY;
            if (tt < NCLS)
                s = lbuf[0][r][tt] + lbuf[1][r][tt] + lbuf[2][r][tt] + lbuf[3][r][tt] + bt[tt];
            v[k] = s;
        }
        float m = fmaxf(fmaxf(v[0], v[1]), fmaxf(v[2], v[3]));
#pragma unroll
        for (int off = 32; off > 0; off >>= 1) m = fmaxf(m, __shfl_xor(m, off));
        float e[4], sum = 0.f;
#pragma unroll
        for (int k = 0; k < 4; ++k) {
            e[k] = (lane + 64 * k < NCLS) ? __expf(v[k] - m) : 0.f;
            sum += e[k];
        }
#pragma unroll
        for (int off = 32; off > 0; off >>= 1) sum += __shfl_xor(sum, off);
        const int ct = cls[sb + r];
#pragma unroll
        for (int k = 0; k < 4; ++k)
            if (lane + 64 * k == ct) tp[sb + r] = e[k] / sum;
    }
}

// ---------------------------------------------------------------------------
// Pass 2: per-class bottom matvec tile + softmax + final product.
// One class per block; 16-sample register tile; 4-way K-split.
// ---------------------------------------------------------------------------
__global__ __launch_bounds__(1024, 4) void bottom_kernel(const float* __restrict__ x,
                                                         const float* __restrict__ Wb,
                                                         const float* __restrict__ bb,
                                                         const int* __restrict__ posArr,
                                                         const float* __restrict__ tpArr,
                                                         const int* __restrict__ list,
                                                         const int* __restrict__ offs,
                                                         float* __restrict__ out) {
    __shared__ float lbuf[4][16][256];    // 64 KB
    const int tid  = threadIdx.x;
    const int c    = blockIdx.x;
    const int o    = offs[c];
    const int n    = offs[c + 1] - o;
    const int g    = __builtin_amdgcn_readfirstlane(tid >> 8);
    const int t    = tid & 255;
    const int tc   = (t < NTPC) ? t : (NTPC - 1);
    const int w    = tid >> 6, lane = tid & 63;
    const float* wcls = Wb + (size_t)c * (NHID * NTPC);

    for (int tb = 0; tb * 16 < n; ++tb) {
        int sid[16];
#pragma unroll
        for (int i = 0; i < 16; ++i) {
            int idx = tb * 16 + i;
            int s_  = (idx < n) ? list[o + idx] : list[o];
            sid[i]  = __builtin_amdgcn_readfirstlane(s_);
        }
        float acc[16];
#pragma unroll
        for (int i = 0; i < 16; ++i) acc[i] = 0.f;

        const float* wb2 = wcls + (size_t)(g * 256) * NTPC + tc;
        const float* xg  = x + g * 256;

#pragma unroll 4
        for (int h = 0; h < 256; ++h) {
            float wv = wb2[(size_t)h * NTPC];
#pragma unroll
            for (int i = 0; i < 16; ++i)
                acc[i] = fmaf(xg[sid[i] * NHID + h], wv, acc[i]);  // uniform x
        }
#pragma unroll
        for (int i = 0; i < 16; ++i) lbuf[g][i][t] = acc[i];
        __syncthreads();

        {   // wave r reduces sample row r of this tile
            const int r = __builtin_amdgcn_readfirstlane(w);
            const int idx = tb * 16 + r;
            if (idx < n) {
                const int s_ = list[o + idx];
                float v[4];
#pragma unroll
                for (int k = 0; k < 4; ++k) {
                    int tt = lane + 64 * k;
                    float s = -INFINITY;
                    if (tt < NTPC)
                        s = lbuf[0][r][tt] + lbuf[1][r][tt] + lbuf[2][r][tt] + lbuf[3][r][tt]
                            + bb[c * NTPC + tt];
                    v[k] = s;
                }
                float m = fmaxf(fmaxf(v[0], v[1]), fmaxf(v[2], v[3]));
#pragma unroll
                for (int off = 32; off > 0; off >>= 1) m = fmaxf(m, __shfl_xor(m, off));
                float e[4], sum = 0.f;
#pragma unroll
                for (int k = 0; k < 4; ++k) {
                    e[k] = (lane + 64 * k < NTPC) ? __expf(v[k] - m) : 0.f;
                    sum += e[k];
                }
#pragma unroll
                for (int off = 32; off > 0; off >>= 1) sum += __shfl_xor(sum, off);
                const int p  = posArr[s_];
                const float tv = tpArr[s_];
#pragma unroll
                for (int k = 0; k < 4; ++k)
                    if (lane + 64 * k == p) out[s_] = tv * e[k] / sum;
            }
        }
        __syncthreads();
    }
}

extern "C" void kernel_launch(void* const* d_in, const int* in_sizes, int n_in,
                              void* d_out, int out_size, void* d_ws, size_t ws_size,
                              hipStream_t stream) {
    const float* inputs = (const float*)d_in[0];
    const int*   labels = (const int*)d_in[1];
    const float* topW   = (const float*)d_in[2];
    const float* topB   = (const float*)d_in[3];
    const float* botW   = (const float*)d_in[4];
    const float* botB   = (const float*)d_in[5];
    float* out = (float*)d_out;

    char* ws   = (char*)d_ws;
    float* tp  = (float*)(ws);
    int*   cls = (int*)(ws + 8192);
    int*   pos = (int*)(ws + 16384);
    int*   lst = (int*)(ws + 24576);
    int*   off = (int*)(ws + 32768);

    group_kernel<<<1, 256, 0, stream>>>(labels, cls, pos, lst, off);
    top_kernel<<<256, 1024, 0, stream>>>(inputs, topW, topB, cls, tp);
    bottom_kernel<<<224, 1024, 0, stream>>>(inputs, botW, botB, pos, tp, lst, off, out);
}